// Round 3
// baseline (654.295 us; speedup 1.0000x reference)
//
#include <hip/hip_runtime.h>
#include <hip/hip_cooperative_groups.h>
#include <math.h>

// Problem constants (b=2, f=8, c=64, h=256, w=256)
#define BF    16          // b*f
#define CH    64          // channels
#define HW    65536       // h*w

// Native clang vector type — required by __builtin_nontemporal_load/store
typedef float vfloat4 __attribute__((ext_vector_type(4)));

// ---------------------------------------------------------------------------
// Fused cooperative kernel.
// Phase 1: ksum[ch] = sum_xy nbr[ch, xy]   (ch = bf*CH + c, 1024 flat channels)
//   1024 blocks, one contiguous 256 KiB channel per block, NT float4 loads.
// grid.sync()  (cooperative; agent-scope atomics for cross-XCD visibility)
// Phase 2: out[bf, xy] = sigmoid( sum_c ref[bf, c, xy] * ksum[bf*CH + c] )
//   same 1024 blocks re-mapped: bf = blk>>6, pix_blk = blk&63, 4 px/thread.
// ---------------------------------------------------------------------------
__global__ __launch_bounds__(256) void fused_kernel(
    const float* __restrict__ nbr, const float* __restrict__ ref,
    float* __restrict__ out, float* __restrict__ ksum) {
    const int tid = threadIdx.x;

    // ---------------- Phase 1: channel sums of nbr ----------------
    {
        const int ch = blockIdx.x;               // 0 .. BF*CH-1
        const vfloat4* base = (const vfloat4*)(nbr + (size_t)ch * HW);
        float sum = 0.f;
#pragma unroll 16
        for (int k = 0; k < HW / (256 * 4); ++k) {   // 64 iters, 16 in flight
            vfloat4 v = __builtin_nontemporal_load(&base[tid + k * 256]);
            sum += (v.x + v.y) + (v.z + v.w);
        }
#pragma unroll
        for (int off = 32; off > 0; off >>= 1)
            sum += __shfl_down(sum, off, 64);

        __shared__ float red[4];
        const int lane = tid & 63, wv = tid >> 6;
        if (lane == 0) red[wv] = sum;
        __syncthreads();
        if (tid == 0) {
            float v = (red[0] + red[1]) + (red[2] + red[3]);
            // agent scope: visible across XCD L2s after the grid barrier
            __hip_atomic_store(&ksum[ch], v, __ATOMIC_RELEASE,
                               __HIP_MEMORY_SCOPE_AGENT);
        }
    }

    cooperative_groups::this_grid().sync();

    // ---------------- Phase 2: weight = sigmoid(ref . ksum) ----------------
    {
        const int bf      = blockIdx.x >> 6;     // 1024 blocks / 64 per bf
        const int pix_blk = blockIdx.x & 63;

        __shared__ float ks[CH];
        if (tid < CH)
            ks[tid] = __hip_atomic_load(&ksum[(size_t)bf * CH + tid],
                                        __ATOMIC_ACQUIRE,
                                        __HIP_MEMORY_SCOPE_AGENT);
        __syncthreads();

        const size_t xy0 = (size_t)pix_blk * 1024 + (size_t)tid * 4;
        const float* refbase = ref + (size_t)bf * CH * HW + xy0;

        vfloat4 acc0 = {0.f, 0.f, 0.f, 0.f};
        vfloat4 acc1 = {0.f, 0.f, 0.f, 0.f};
#pragma unroll 8
        for (int c = 0; c < CH; c += 2) {
            vfloat4 r0 = __builtin_nontemporal_load(
                (const vfloat4*)(refbase + (size_t)c * HW));
            vfloat4 r1 = __builtin_nontemporal_load(
                (const vfloat4*)(refbase + (size_t)(c + 1) * HW));
            const float k0 = ks[c], k1 = ks[c + 1];
            acc0.x = fmaf(r0.x, k0, acc0.x);
            acc0.y = fmaf(r0.y, k0, acc0.y);
            acc0.z = fmaf(r0.z, k0, acc0.z);
            acc0.w = fmaf(r0.w, k0, acc0.w);
            acc1.x = fmaf(r1.x, k1, acc1.x);
            acc1.y = fmaf(r1.y, k1, acc1.y);
            acc1.z = fmaf(r1.z, k1, acc1.z);
            acc1.w = fmaf(r1.w, k1, acc1.w);
        }

        vfloat4 o;
        o.x = 1.f / (1.f + __expf(-(acc0.x + acc1.x)));
        o.y = 1.f / (1.f + __expf(-(acc0.y + acc1.y)));
        o.z = 1.f / (1.f + __expf(-(acc0.z + acc1.z)));
        o.w = 1.f / (1.f + __expf(-(acc0.w + acc1.w)));

        __builtin_nontemporal_store(o, (vfloat4*)(out + (size_t)bf * HW + xy0));
    }
}

// ---------------------------------------------------------------------------
// Fallback path (proven round-2 kernels) in case cooperative launch is
// rejected under graph capture.
// ---------------------------------------------------------------------------
__global__ __launch_bounds__(256) void ksum_kernel(
    const float* __restrict__ nbr, float* __restrict__ ksum) {
    const int ch  = blockIdx.x;
    const int tid = threadIdx.x;
    const vfloat4* base = (const vfloat4*)(nbr + (size_t)ch * HW);
    float sum = 0.f;
#pragma unroll 8
    for (int k = 0; k < HW / (256 * 4); ++k) {
        vfloat4 v = __builtin_nontemporal_load(&base[tid + k * 256]);
        sum += (v.x + v.y) + (v.z + v.w);
    }
#pragma unroll
    for (int off = 32; off > 0; off >>= 1)
        sum += __shfl_down(sum, off, 64);
    __shared__ float red[4];
    const int lane = tid & 63, wv = tid >> 6;
    if (lane == 0) red[wv] = sum;
    __syncthreads();
    if (tid == 0)
        ksum[ch] = (red[0] + red[1]) + (red[2] + red[3]);
}

__global__ __launch_bounds__(256) void weight_kernel(
    const float* __restrict__ ref, const float* __restrict__ ksum,
    float* __restrict__ out) {
    const int blocksPerBF = HW / (256 * 4);
    const int bf      = blockIdx.x / blocksPerBF;
    const int pix_blk = blockIdx.x % blocksPerBF;
    const int tid     = threadIdx.x;

    __shared__ float ks[CH];
    if (tid < CH)
        ks[tid] = ksum[(size_t)bf * CH + tid];
    __syncthreads();

    const size_t xy0 = (size_t)pix_blk * 1024 + (size_t)tid * 4;
    const float* refbase = ref + (size_t)bf * CH * HW + xy0;

    vfloat4 acc0 = {0.f, 0.f, 0.f, 0.f};
    vfloat4 acc1 = {0.f, 0.f, 0.f, 0.f};
#pragma unroll 8
    for (int c = 0; c < CH; c += 2) {
        vfloat4 r0 = __builtin_nontemporal_load(
            (const vfloat4*)(refbase + (size_t)c * HW));
        vfloat4 r1 = __builtin_nontemporal_load(
            (const vfloat4*)(refbase + (size_t)(c + 1) * HW));
        const float k0 = ks[c], k1 = ks[c + 1];
        acc0.x = fmaf(r0.x, k0, acc0.x);
        acc0.y = fmaf(r0.y, k0, acc0.y);
        acc0.z = fmaf(r0.z, k0, acc0.z);
        acc0.w = fmaf(r0.w, k0, acc0.w);
        acc1.x = fmaf(r1.x, k1, acc1.x);
        acc1.y = fmaf(r1.y, k1, acc1.y);
        acc1.z = fmaf(r1.z, k1, acc1.z);
        acc1.w = fmaf(r1.w, k1, acc1.w);
    }

    vfloat4 o;
    o.x = 1.f / (1.f + __expf(-(acc0.x + acc1.x)));
    o.y = 1.f / (1.f + __expf(-(acc0.y + acc1.y)));
    o.z = 1.f / (1.f + __expf(-(acc0.z + acc1.z)));
    o.w = 1.f / (1.f + __expf(-(acc0.w + acc1.w)));

    __builtin_nontemporal_store(o, (vfloat4*)(out + (size_t)bf * HW + xy0));
}

// ---------------------------------------------------------------------------
extern "C" void kernel_launch(void* const* d_in, const int* in_sizes, int n_in,
                              void* d_out, int out_size, void* d_ws, size_t ws_size,
                              hipStream_t stream) {
    const float* nbr = (const float*)d_in[0];
    const float* ref = (const float*)d_in[1];
    float* out       = (float*)d_out;
    float* ksum      = (float*)d_ws;   // BF*CH floats = 4 KB

    void* args[] = {(void*)&nbr, (void*)&ref, (void*)&out, (void*)&ksum};
    hipError_t err = hipLaunchCooperativeKernel(
        (const void*)fused_kernel, dim3(BF * CH), dim3(256), args, 0, stream);
    if (err != hipSuccess) {
        // Fallback: proven two-kernel path
        ksum_kernel<<<BF * CH, 256, 0, stream>>>(nbr, ksum);
        weight_kernel<<<BF * (HW / 1024), 256, 0, stream>>>(ref, ksum, out);
    }
}

// Round 4
// 473.740 us; speedup vs baseline: 1.3811x; 1.3811x over previous
//
#include <hip/hip_runtime.h>
#include <math.h>

// Problem constants (b=2, f=8, c=64, h=256, w=256)
#define BF    16          // b*f
#define CH    64          // channels
#define HW    65536       // h*w

// Native clang vector type — required by __builtin_nontemporal_load/store
typedef float vfloat4 __attribute__((ext_vector_type(4)));

// ---------------------------------------------------------------------------
// Kernel 1: ksum[bf*CH + c] = sum_xy nbr[bf, c, xy]
// grid = BF*CH = 1024 blocks (one per channel, all resident: 4 blocks/CU),
// 256 threads. Each block streams one contiguous 256 KiB channel with
// NONTEMPORAL float4 loads (no L2 allocation -> no dirty-line evictions of
// the harness's 1 GiB poison fill), reduces once, writes the final sum.
//
// Measured (R2/R3 decomposition): both kernels combined ~79 us for 516 MiB
// read + 4 MiB write = ~6.5 TB/s effective (>= 6.3 TB/s achievable ceiling;
// excess from LLC absorption, confirmed by FETCH_SIZE=268 MB on the fused
// variant). Do NOT fuse with grid.sync(): cross-XCD barrier + agent-scope
// release/acquire cost ~180 us (R3: 258 us fused vs 79 us split).
// ---------------------------------------------------------------------------
__global__ __launch_bounds__(256) void ksum_kernel(
    const float* __restrict__ nbr, float* __restrict__ ksum) {
    const int ch  = blockIdx.x;          // 0 .. BF*CH-1
    const int tid = threadIdx.x;

    const vfloat4* base = (const vfloat4*)(nbr + (size_t)ch * HW);
    float sum = 0.f;
#pragma unroll 8
    for (int k = 0; k < HW / (256 * 4); ++k) {   // 64 iters, 8 loads in flight
        vfloat4 v = __builtin_nontemporal_load(&base[tid + k * 256]);
        sum += (v.x + v.y) + (v.z + v.w);
    }
    // wave-64 shuffle reduction
#pragma unroll
    for (int off = 32; off > 0; off >>= 1)
        sum += __shfl_down(sum, off, 64);

    __shared__ float red[4];
    const int lane = tid & 63, wv = tid >> 6;
    if (lane == 0) red[wv] = sum;
    __syncthreads();
    if (tid == 0)
        ksum[ch] = (red[0] + red[1]) + (red[2] + red[3]);
}

// ---------------------------------------------------------------------------
// Kernel 2: weight[bf, xy] = sigmoid( sum_c ref[bf, c, xy] * ksum[bf, c] )
// grid = BF * (HW / 1024) = 1024 blocks (all resident), 256 threads;
// 4 pixels (float4) per thread. 2-channel unroll x8 => 16 NT loads in flight.
// ---------------------------------------------------------------------------
__global__ __launch_bounds__(256) void weight_kernel(
    const float* __restrict__ ref, const float* __restrict__ ksum,
    float* __restrict__ out) {
    const int blocksPerBF = HW / (256 * 4);      // 64
    const int bf      = blockIdx.x / blocksPerBF;
    const int pix_blk = blockIdx.x % blocksPerBF;
    const int tid     = threadIdx.x;

    __shared__ float ks[CH];
    if (tid < CH)
        ks[tid] = ksum[(size_t)bf * CH + tid];
    __syncthreads();

    const size_t xy0 = (size_t)pix_blk * 1024 + (size_t)tid * 4;
    const float* refbase = ref + (size_t)bf * CH * HW + xy0;

    vfloat4 acc0 = {0.f, 0.f, 0.f, 0.f};
    vfloat4 acc1 = {0.f, 0.f, 0.f, 0.f};
#pragma unroll 8
    for (int c = 0; c < CH; c += 2) {
        vfloat4 r0 = __builtin_nontemporal_load(
            (const vfloat4*)(refbase + (size_t)c * HW));
        vfloat4 r1 = __builtin_nontemporal_load(
            (const vfloat4*)(refbase + (size_t)(c + 1) * HW));
        const float k0 = ks[c], k1 = ks[c + 1];
        acc0.x = fmaf(r0.x, k0, acc0.x);
        acc0.y = fmaf(r0.y, k0, acc0.y);
        acc0.z = fmaf(r0.z, k0, acc0.z);
        acc0.w = fmaf(r0.w, k0, acc0.w);
        acc1.x = fmaf(r1.x, k1, acc1.x);
        acc1.y = fmaf(r1.y, k1, acc1.y);
        acc1.z = fmaf(r1.z, k1, acc1.z);
        acc1.w = fmaf(r1.w, k1, acc1.w);
    }

    vfloat4 o;
    o.x = 1.f / (1.f + __expf(-(acc0.x + acc1.x)));
    o.y = 1.f / (1.f + __expf(-(acc0.y + acc1.y)));
    o.z = 1.f / (1.f + __expf(-(acc0.z + acc1.z)));
    o.w = 1.f / (1.f + __expf(-(acc0.w + acc1.w)));

    __builtin_nontemporal_store(o, (vfloat4*)(out + (size_t)bf * HW + xy0));
}

// ---------------------------------------------------------------------------
extern "C" void kernel_launch(void* const* d_in, const int* in_sizes, int n_in,
                              void* d_out, int out_size, void* d_ws, size_t ws_size,
                              hipStream_t stream) {
    const float* nbr = (const float*)d_in[0];
    const float* ref = (const float*)d_in[1];
    float* out       = (float*)d_out;
    float* ksum      = (float*)d_ws;   // BF*CH floats = 4 KB

    ksum_kernel<<<BF * CH, 256, 0, stream>>>(nbr, ksum);
    weight_kernel<<<BF * (HW / 1024), 256, 0, stream>>>(ref, ksum, out);
}